// Round 2
// baseline (1374.258 us; speedup 1.0000x reference)
//
#include <hip/hip_runtime.h>
#include <math.h>

namespace {

typedef short short8 __attribute__((ext_vector_type(8)));
typedef float f32x16 __attribute__((ext_vector_type(16)));

constexpr int NEX  = 256;
constexpr int LLEN = 2048;
constexpr int FEATS = 8192;
constexpr int PAD_L = 512;
constexpr int PAD_R = 1536;           // covers taps up to j=15 (padded-K reads)
constexpr int XSZ = PAD_L + LLEN + PAD_R; // 4096

// round-to-nearest-even bf16 high part; also returns its float value
__device__ __forceinline__ ushort bf16_rne(float x, float& hf) {
  uint b = __float_as_uint(x);
  uint r = b + 0x7fffu + ((b >> 16) & 1u);
  ushort h = (ushort)(r >> 16);
  hf = __uint_as_float(((uint)h) << 16);
  return h;
}

template<int D, int DI>
__device__ __forceinline__ void body(
    const float* __restrict__ X, const float* __restrict__ W,
    float* __restrict__ out, float* xs, uint* xhl)
{
  const int n    = blockIdx.x;
  const int diff = blockIdx.y;       // 0: X, 1: diff(X)
  const int tid  = threadIdx.x;
  const int lane = tid & 63, wave = tid >> 6;
  const int col  = lane & 31, hi = lane >> 5;

  // bins alias the xs area (xs is dead after the bf16 split)
  float* binsM = xs;                 // [256 kern][4 sub]
  int*   binsN = (int*)(xs + 1024);  // [256 kern][4 sub]

  // ---- stage padded X row (fp32) ----
  {
    const float4 z4 = {0.f, 0.f, 0.f, 0.f};
    for (int i = tid; i < PAD_L / 4; i += 256) ((float4*)xs)[i] = z4;
    for (int i = tid; i < PAD_R / 4; i += 256)
      ((float4*)(xs + PAD_L + LLEN))[i] = z4;
    const float4* xrow = (const float4*)(X + n * LLEN);
    for (int i = tid; i < LLEN / 4; i += 256)
      ((float4*)(xs + PAD_L))[i] = xrow[i];
  }
  __syncthreads();

  // ---- on-the-fly diff + bf16 hi/lo split, packed (lo<<16 | hi) ----
  for (int i = tid; i < XSZ; i += 256) {
    float x;
    if (diff) x = (i >= PAD_L && i < PAD_L + LLEN - 1) ? (xs[i + 1] - xs[i]) : 0.f;
    else      x = xs[i];
    float hf, d2;
    ushort hb = bf16_rne(x, hf);
    ushort lb = bf16_rne(x - hf, d2);
    xhl[i] = (uint)hb | ((uint)lb << 16);
  }
  __syncthreads();

  // ---- init bins (overwrites xs area) ----
  for (int i = tid; i < 1024; i += 256) { binsM[i] = 0.f; binsN[i] = 0; }
  __syncthreads();

  const float* wbase = W + (DI * 2 + diff) * 256 * 9;

  for (int kt = 0; kt < 8; ++kt) {
    // A fragments: W[kern = kt*32 + col][j], j = hi*8 + e, zero-padded j>=9.
    // bf16 hi/lo pair.
    short8 ah, al;
    {
      const float* wrow = wbase + (kt * 32 + col) * 9;
      #pragma unroll
      for (int e = 0; e < 8; ++e) {
        int j = hi * 8 + e;
        float wv = (j < 9) ? wrow[j] : 0.f;
        float hf, d2;
        ushort hb = bf16_rne(wv, hf);
        ushort lb = bf16_rne(wv - hf, d2);
        ah[e] = (short)hb;
        al[e] = (short)lb;
      }
    }

    float accM[16];
    int   accN[16];
    #pragma unroll
    for (int i = 0; i < 16; ++i) { accM[i] = 0.f; accN[i] = 0; }

    for (int tti = 0; tti < 16; ++tti) {
      const int tt = (tti << 2) | wave;          // this wave's t-tile
      // B fragment: B[j = hi*8+e][col] = x[tt*32 + col + (j-4)*D]
      const int ebase = PAD_L + tt * 32 + col + (hi * 8 - 4) * D;
      short8 bh, bl;
      #pragma unroll
      for (int e = 0; e < 8; ++e) {
        uint u = xhl[ebase + e * D];
        bh[e] = (short)(u & 0xffffu);
        bl[e] = (short)(u >> 16);
      }

      f32x16 c;
      #pragma unroll
      for (int i = 0; i < 16; ++i) c[i] = 0.f;
      // (xh+xl)*(wh+wl) ~= wh*xh + wh*xl + wl*xh  (lo*lo dropped, ~1e-5 rel)
      c = __builtin_amdgcn_mfma_f32_32x32x16_bf16(al, bh, c, 0, 0, 0);
      c = __builtin_amdgcn_mfma_f32_32x32x16_bf16(ah, bl, c, 0, 0, 0);
      c = __builtin_amdgcn_mfma_f32_32x32x16_bf16(ah, bh, c, 0, 0, 0);

      // C layout: col(lane&31)=t, row=(reg&3)+8*(reg>>2)+4*hi = kernel.
      // Lane holds k={0..3}+4*hi of h = reg>>2 (4 h-groups).
      float zx[4], zn[4];
      #pragma unroll
      for (int h = 0; h < 4; ++h) {
        float m4 = fmaxf(fmaxf(c[4*h], c[4*h+1]), fmaxf(c[4*h+2], c[4*h+3]));
        zx[h] = fmaxf(m4, __shfl_xor(m4, 32));
        float n4 = fminf(fminf(c[4*h], c[4*h+1]), fminf(c[4*h+2], c[4*h+3]));
        zn[h] = fminf(n4, __shfl_xor(n4, 32));
      }
      // diff branch has only 2047 valid timesteps: mask t==2047 (tt=63,col=31)
      if (diff && tt == 63 && col == 31) {
        #pragma unroll
        for (int h = 0; h < 4; ++h) {
          zx[h] = __builtin_inff();
          zn[h] = -__builtin_inff();
        }
      }
      #pragma unroll
      for (int i = 0; i < 16; ++i) {
        int h = i >> 2;
        accM[i] += (c[i] == zx[h]) ? c[i] : 0.f;
        accN[i] += (c[i] == zn[h]) ? 1 : 0;
      }
    }

    // flush this kern-tile into 4-way split LDS bins (8-way atomic conflicts)
    const int sub = (lane >> 3) & 3;
    #pragma unroll
    for (int i = 0; i < 16; ++i) {
      int row  = (i & 3) + 8 * (i >> 2) + 4 * hi;
      int kern = kt * 32 + row;
      atomicAdd(&binsM[kern * 4 + sub], accM[i]);
      atomicAdd(&binsN[kern * 4 + sub], accN[i]);
    }
  }
  __syncthreads();

  if (tid < 256) {
    float vM = binsM[tid*4] + binsM[tid*4+1] + binsM[tid*4+2] + binsM[tid*4+3];
    float vN = (float)(binsN[tid*4] + binsN[tid*4+1] +
                       binsN[tid*4+2] + binsN[tid*4+3]);
    const int base = n * FEATS + (DI * 4 + diff * 2) * 256 + tid;
    out[base]       = vM > 0.f ? sqrtf(vM) : 0.f;  // count_max
    out[base + 256] = vN > 0.f ? sqrtf(vN) : 0.f;  // count_min
  }
}

__global__ __launch_bounds__(256, 4) void hydra_kernel(
    const float* __restrict__ X, const float* __restrict__ W,
    float* __restrict__ out)
{
  __shared__ float xs[XSZ];    // 16 KB (reused as bins)
  __shared__ uint  xhl[XSZ];   // 16 KB packed bf16 hi|lo
  switch (blockIdx.z) {
    case 0: body<1,   0>(X, W, out, xs, xhl); break;
    case 1: body<2,   1>(X, W, out, xs, xhl); break;
    case 2: body<4,   2>(X, W, out, xs, xhl); break;
    case 3: body<8,   3>(X, W, out, xs, xhl); break;
    case 4: body<16,  4>(X, W, out, xs, xhl); break;
    case 5: body<32,  5>(X, W, out, xs, xhl); break;
    case 6: body<64,  6>(X, W, out, xs, xhl); break;
    case 7: body<128, 7>(X, W, out, xs, xhl); break;
  }
}

} // namespace

extern "C" void kernel_launch(void* const* d_in, const int* in_sizes, int n_in,
                              void* d_out, int out_size, void* d_ws, size_t ws_size,
                              hipStream_t stream) {
  const float* X = (const float*)d_in[0];
  const float* W = (const float*)d_in[1];
  float* out = (float*)d_out;
  dim3 grid(NEX, 2, 8);
  hipLaunchKernelGGL(hydra_kernel, grid, dim3(256), 0, stream, X, W, out);
}

// Round 3
// 568.308 us; speedup vs baseline: 2.4182x; 2.4182x over previous
//
#include <hip/hip_runtime.h>
#include <math.h>

namespace {

typedef short short8 __attribute__((ext_vector_type(8)));
typedef float f32x16 __attribute__((ext_vector_type(16)));
typedef unsigned int u32;

constexpr int NEX = 256, LLEN = 2048, FEATS = 8192;
constexpr int PL = 512;          // 4*Dmax zeros on the left
constexpr int XSZ = 4096;        // PL + 2048 + 1408 pad-right, rounded

// packed bf16 split: (lo_bf16 << 16) | hi_bf16, both RNE
__device__ __forceinline__ u32 bfsplit(float x) {
  u32 b = __float_as_uint(x);
  u32 hb = (b + 0x7fffu + ((b >> 16) & 1u)) >> 16;
  float lo = x - __uint_as_float(hb << 16);
  u32 b2 = __float_as_uint(lo);
  u32 lb = (b2 + 0x7fffu + ((b2 >> 16) & 1u)) >> 16;
  return hb | (lb << 16);
}

// broadcast max/min across the lane<32 / lane>=32 halves using
// v_permlane32_swap (VALU). Works under either half-ordering semantics:
// with both operands = m, results are {lo-bcast, hi-bcast} in some order.
__device__ __forceinline__ float bcast_max(float m) {
  float mc;
  asm("v_mov_b32 %0, %1" : "=v"(mc) : "v"(m));           // opaque copy: distinct reg
  asm("v_permlane32_swap_b32 %0, %1" : "+v"(m), "+v"(mc));
  return fmaxf(m, mc);
}
__device__ __forceinline__ float bcast_min(float m) {
  float mc;
  asm("v_mov_b32 %0, %1" : "=v"(mc) : "v"(m));
  asm("v_permlane32_swap_b32 %0, %1" : "+v"(m), "+v"(mc));
  return fminf(m, mc);
}

template<int D, int DI>
__device__ __forceinline__ void body(
    const float* __restrict__ X, const float* __restrict__ W,
    float* __restrict__ out, u32* xhl, float* scratch, float* fin)
{
  const int n = blockIdx.x, diff = blockIdx.y, tid = threadIdx.x;
  const int lane = tid & 63, wave = tid >> 6;
  const int col = lane & 31, hi = lane >> 5;

  // ---- stage padded input as packed bf16 hi/lo (diff computed on the fly) ----
  const float* xr = X + n * LLEN;
  for (int i = tid; i < XSZ; i += 256) {
    float x = 0.f;
    if (diff) { if (i >= PL && i < PL + LLEN - 1) x = xr[i - PL + 1] - xr[i - PL]; }
    else      { if (i >= PL && i < PL + LLEN)     x = xr[i - PL]; }
    xhl[i] = bfsplit(x);
  }
  __syncthreads();

  float* sw = scratch + wave * 1024;                  // per-wave [32][32] transpose
  const float* wall = W + (DI * 2 + diff) * (256 * 9);

  for (int kt2 = 0; kt2 < 2; ++kt2) {
    const int kbase = wave * 64 + kt2 * 32;           // this wave's kern tile
    // A fragments: A[row=col -> kern kbase+col][j = 8*hi+e], taps padded 9->16
    short8 ah, al;
    {
      const float* wrow = wall + (kbase + col) * 9;
      #pragma unroll
      for (int e = 0; e < 8; ++e) {
        int j = hi * 8 + e;
        float wv = (j < 9) ? wrow[j] : 0.f;
        u32 p = bfsplit(wv);
        ah[e] = (short)(p & 0xffffu);
        al[e] = (short)(p >> 16);
      }
    }

    float accM[16];
    int   accN[16];
    #pragma unroll
    for (int i = 0; i < 16; ++i) { accM[i] = 0.f; accN[i] = 0; }

    #pragma unroll 2
    for (int tt = 0; tt < 64; ++tt) {
      // B fragment: B[j=8*hi+e][col] = x[tt*32 + col + (j-4)*D]
      const int ebase = PL + tt * 32 + col + (hi * 8 - 4) * D;
      u32 uu[8];
      #pragma unroll
      for (int e = 0; e < 8; ++e) uu[e] = xhl[ebase + e * D];
      union { short8 s; u32 u[4]; } bh, bl;
      #pragma unroll
      for (int p = 0; p < 4; ++p) {
        bh.u[p] = __builtin_amdgcn_perm(uu[2*p+1], uu[2*p], 0x05040100u);
        bl.u[p] = __builtin_amdgcn_perm(uu[2*p+1], uu[2*p], 0x07060302u);
      }

      f32x16 c = {};
      // (wh+wl)(xh+xl) ~= wl*xh + wh*xl + wh*xh (lo*lo dropped)
      c = __builtin_amdgcn_mfma_f32_32x32x16_bf16(al, bh.s, c, 0, 0, 0);
      c = __builtin_amdgcn_mfma_f32_32x32x16_bf16(ah, bl.s, c, 0, 0, 0);
      c = __builtin_amdgcn_mfma_f32_32x32x16_bf16(ah, bh.s, c, 0, 0, 0);

      // C layout: col=lane&31=t, row=(i&3)+8*(i>>2)+4*hi = local kern.
      // Quad q holds k = 4*hi+(i&3) of h-group q; partner half has the other 4 k.
      float zx[4], zn[4];
      #pragma unroll
      for (int q = 0; q < 4; ++q) {
        float mx = fmaxf(fmaxf(fmaxf(c[4*q], c[4*q+1]), c[4*q+2]), c[4*q+3]);
        zx[q] = bcast_max(mx);
        float mn = fminf(fminf(fminf(c[4*q], c[4*q+1]), c[4*q+2]), c[4*q+3]);
        zn[q] = bcast_min(mn);
      }
      #pragma unroll
      for (int i = 0; i < 16; ++i) {
        int q = i >> 2;
        accM[i] += (c[i] == zx[q]) ? c[i] : 0.f;
        accN[i] += (c[i] == zn[q]) ? 1 : 0;
      }
    }

    // ---- flush: wave-private XOR-swizzled transpose, M round then N round ----
    #pragma unroll
    for (int i = 0; i < 16; ++i) {
      int s = (i & 3) + 8 * (i >> 2) + 4 * hi;
      sw[s * 32 + (col ^ s)] = accM[i];
    }
    float sM = 0.f, sN = 0.f;
    if (lane < 32) {
      #pragma unroll
      for (int j = 0; j < 32; ++j) sM += sw[lane * 32 + (j ^ lane)];
    }
    #pragma unroll
    for (int i = 0; i < 16; ++i) {
      int s = (i & 3) + 8 * (i >> 2) + 4 * hi;
      sw[s * 32 + (col ^ s)] = (float)accN[i];
    }
    if (lane < 32) {
      #pragma unroll
      for (int j = 0; j < 32; ++j) sN += sw[lane * 32 + (j ^ lane)];
      // fin[wave][r=lane][kt2] = {M, N}
      *(float2*)(fin + ((wave * 32 + lane) * 2 + kt2) * 2) = make_float2(sM, sN);
    }
  }
  __syncthreads();

  // ---- final: tid = kern. Single owner per kern -> no cross-wave sum ----
  const int w2 = tid >> 6, kt2f = (tid >> 5) & 1, r = tid & 31;
  float2 mn2 = *(const float2*)(fin + ((w2 * 32 + r) * 2 + kt2f) * 2);
  float M = mn2.x, N = mn2.y;

  if (diff) {
    // remove the spurious t=2047 column (diff branch has only 2047 timesteps)
    const float* wrow = wall + tid * 9;
    float z = 0.f;
    #pragma unroll
    for (int j = 0; j < 9; ++j) {
      u32 u = xhl[PL + (LLEN - 1) + (j - 4) * D];
      float xh = __uint_as_float((u & 0xffffu) << 16);
      float xl = __uint_as_float((u >> 16) << 16);
      u32 wp = bfsplit(wrow[j]);
      float wh = __uint_as_float((wp & 0xffffu) << 16);
      float wl = __uint_as_float((wp >> 16) << 16);
      z += wh * xh + wh * xl + wl * xh;
    }
    float* zrow = scratch;                       // safe to reuse after barrier
    zrow[tid] = z;
    __syncthreads();
    const int h8 = tid & ~7;
    float zxv = zrow[h8], znv = zrow[h8];
    #pragma unroll
    for (int j = 1; j < 8; ++j) {
      zxv = fmaxf(zxv, zrow[h8 + j]);
      znv = fminf(znv, zrow[h8 + j]);
    }
    M -= (z == zxv) ? z : 0.f;
    N -= (z == znv) ? 1.f : 0.f;
  }

  const int base = n * FEATS + (DI * 4 + diff * 2) * 256 + tid;
  out[base]       = M > 0.f ? sqrtf(M) : 0.f;    // count_max
  out[base + 256] = N > 0.f ? sqrtf(N) : 0.f;    // count_min
}

__global__ __launch_bounds__(256, 4) void hydra_kernel(
    const float* __restrict__ X, const float* __restrict__ W,
    float* __restrict__ out)
{
  __shared__ u32   xhl[XSZ];        // 16 KB packed bf16 hi|lo
  __shared__ float scratch[4096];   // 16 KB: 4 waves x [32][32] transpose
  __shared__ float fin[512];        // 2 KB:  [4][32][2]{M,N}
  switch (blockIdx.z) {
    case 0: body<1,   0>(X, W, out, xhl, scratch, fin); break;
    case 1: body<2,   1>(X, W, out, xhl, scratch, fin); break;
    case 2: body<4,   2>(X, W, out, xhl, scratch, fin); break;
    case 3: body<8,   3>(X, W, out, xhl, scratch, fin); break;
    case 4: body<16,  4>(X, W, out, xhl, scratch, fin); break;
    case 5: body<32,  5>(X, W, out, xhl, scratch, fin); break;
    case 6: body<64,  6>(X, W, out, xhl, scratch, fin); break;
    case 7: body<128, 7>(X, W, out, xhl, scratch, fin); break;
  }
}

} // namespace

extern "C" void kernel_launch(void* const* d_in, const int* in_sizes, int n_in,
                              void* d_out, int out_size, void* d_ws, size_t ws_size,
                              hipStream_t stream) {
  const float* X = (const float*)d_in[0];
  const float* W = (const float*)d_in[1];
  float* out = (float*)d_out;
  dim3 grid(NEX, 2, 8);
  hipLaunchKernelGGL(hydra_kernel, grid, dim3(256), 0, stream, X, W, out);
}